// Round 13
// baseline (347.188 us; speedup 1.0000x reference)
//
#include <hip/hip_runtime.h>
#include <hip/hip_bf16.h>

#define TOKENS 8192
#define DM 512
#define NE 8
#define HID 1024
#define NSLOT (TOKENS * 2)
#define NB 32          // token chunks for sortbuild (256 tokens each)

#define BM 128
#define BN 64
#define BK 64
#define BN2 128        // gemm2 N-tile
#define MAXTILE 136    // 8 * 17, > sum ceil(counts[e]/BM) worst case (135)

typedef __bf16 bf16x8 __attribute__((ext_vector_type(8)));
typedef float floatx4 __attribute__((ext_vector_type(4)));
typedef unsigned short u16x8 __attribute__((ext_vector_type(8)));

__device__ __forceinline__ unsigned short f2bf(float f) {
    union { float f; unsigned u; } c; c.f = f;
    unsigned u = c.u;
    u += 0x7fffu + ((u >> 16) & 1u);   // RNE
    return (unsigned short)(u >> 16);
}

// async global->LDS, 16B per lane, LDS dest = wave-uniform base + lane*16
__device__ __forceinline__ void load16_lds(const void* g, void* l) {
    __builtin_amdgcn_global_load_lds(
        (const __attribute__((address_space(1))) unsigned int*)g,
        (__attribute__((address_space(3))) unsigned int*)l, 16, 0, 0);
}

// ------- prep: fused weight-convert/transpose + router ----------------------
// blocks [0,3072): all 3 weights [E][K][N] fp32 -> [E][N][K] bf16 (64x64 tiles)
// blocks [3072,5120): router (fp32 logits, top-2, softmax over 2) + x->bf16.
// [R6-R8: grid-wide sync (cooperative or spin-barrier) is off the table on
// this 8-XCD part. Point-to-point atomic handoff (no waiting) is allowed.]
__global__ void prep_kernel(const float* __restrict__ x, const float* __restrict__ Wg,
                            const float* __restrict__ bg,
                            const float* __restrict__ W1, const float* __restrict__ W3,
                            const float* __restrict__ W2,
                            unsigned short* __restrict__ w1t, unsigned short* __restrict__ w3t,
                            unsigned short* __restrict__ w2t,
                            int* __restrict__ top_idx, float* __restrict__ top_p,
                            unsigned short* __restrict__ xb) {
    if (blockIdx.x < 3072) {
        // ---------- cvt/transpose role ----------
        __shared__ float tile[64][65];
        const int cb = blockIdx.x;
        const int wsel = cb >> 10;               // 0,1,2
        const float* src; unsigned short* dst; int K, N;
        if (wsel == 0)      { src = W1; dst = w1t; K = DM;  N = HID; }
        else if (wsel == 1) { src = W3; dst = w3t; K = DM;  N = HID; }
        else                { src = W2; dst = w2t; K = HID; N = DM;  }
        const int tkn = (K >> 6) * (N >> 6);     // 128 for all three
        int b = cb & 1023;                       // 0 .. NE*tkn-1 (== 1024)
        int e = b / tkn;
        int rem = b % tkn;
        const int tn6 = N >> 6;
        int kt = rem / tn6, nt = rem % tn6;
        int tx = threadIdx.x & 15, ty = threadIdx.x >> 4;   // 16 x 16
        const float* s = src + ((size_t)(e * K + kt * 64 + ty)) * N + nt * 64 + tx * 4;
        #pragma unroll
        for (int i = 0; i < 4; i++) {
            float4 v = *(const float4*)(s + (size_t)(i * 16) * N);
            float* tr = &tile[ty + i * 16][tx * 4];
            tr[0] = v.x; tr[1] = v.y; tr[2] = v.z; tr[3] = v.w;
        }
        __syncthreads();
        int n = threadIdx.x >> 3;                // 0..31
        int c8 = (threadIdx.x & 7) * 8;          // k offset within tile
        unsigned short* d = dst + ((size_t)(e * N + nt * 64)) * K + kt * 64;
        #pragma unroll
        for (int i = 0; i < 2; i++) {
            int nn = n + i * 32;
            u16x8 r;
            #pragma unroll
            for (int kk = 0; kk < 8; kk++) r[kk] = f2bf(tile[c8 + kk][nn]);
            *(u16x8*)(d + (size_t)nn * K + c8) = r;
        }
    } else {
        // ---------- router role ----------
        int lane = threadIdx.x & 63, wave = threadIdx.x >> 6;
        int t = (blockIdx.x - 3072) * 4 + wave;
        float acc[NE];
        #pragma unroll
        for (int e = 0; e < NE; e++) acc[e] = 0.f;
        const float* xr = x + (size_t)t * DM;
        unsigned short* xbr = xb + (size_t)t * DM;
        #pragma unroll
        for (int j = 0; j < 8; j++) {
            int d = lane + j * 64;
            float xv = xr[d];
            xbr[d] = f2bf(xv);
            const float4* wr = (const float4*)(Wg + (size_t)d * NE);
            float4 w0 = wr[0], w1 = wr[1];
            acc[0] += xv * w0.x; acc[1] += xv * w0.y; acc[2] += xv * w0.z; acc[3] += xv * w0.w;
            acc[4] += xv * w1.x; acc[5] += xv * w1.y; acc[6] += xv * w1.z; acc[7] += xv * w1.w;
        }
        #pragma unroll
        for (int e = 0; e < NE; e++) {
            float v = acc[e];
            #pragma unroll
            for (int off = 32; off > 0; off >>= 1) v += __shfl_down(v, off, 64);
            acc[e] = v;
        }
        if (lane == 0) {
            float best = -1e30f, second = -1e30f;
            int bi = 0, si = 0;
            #pragma unroll
            for (int e = 0; e < NE; e++) {
                float v = acc[e] + bg[e];
                if (v > best) { second = best; si = bi; best = v; bi = e; }
                else if (v > second) { second = v; si = e; }
            }
            float ex = __expf(second - best);
            float inv = 1.f / (1.f + ex);
            top_idx[t * 2] = bi;  top_idx[t * 2 + 1] = si;
            top_p[t * 2] = inv;   top_p[t * 2 + 1] = ex * inv;
        }
    }
}

// ------- sortbuild: hist + prefix + build in ONE node, NO cross-block dep ----
// Each of the 32 blocks redundantly scans ALL 16K top_idx entries (128 KB,
// L2-resident) with packed 8x8-bit per-thread counters. Also zeroes the
// per-token completion counters used by gemm2's fused combine (replay-safe:
// re-zeroed every launch before gemm2 runs). [proven R10]
__global__ void sortbuild_kernel(const int* __restrict__ top_idx, const float* __restrict__ top_p,
                                 int* __restrict__ counts, int* __restrict__ offsets,
                                 int* __restrict__ rows, float* __restrict__ gates,
                                 int* __restrict__ slot_of, int* __restrict__ ctr) {
    __shared__ int cntAll[NE], cntBef[NE], cur[NE];
    const int b = blockIdx.x, tid = threadIdx.x;
    const int lane = tid & 63;
    ctr[b * 256 + tid] = 0;                        // 32*256 == TOKENS exactly
    if (tid < NE) { cntAll[tid] = 0; cntBef[tid] = 0; }
    __syncthreads();

    unsigned long long aAll = 0ull, aBef = 0ull;
    for (int k = 0; k < TOKENS / 256; k++) {       // 32 iterations
        int t = k * 256 + tid;
        int2 ei = *(const int2*)(top_idx + (size_t)t * 2);
        unsigned long long inc = (1ull << (ei.x * 8)) + (1ull << (ei.y * 8));
        aAll += inc;
        if (k < b) aBef += inc;                    // wave-uniform predicate
    }
    auto unpackLo = [](unsigned long long a) {
        return ( a        & 0xFFull)        | ((( a >> 8 ) & 0xFFull) << 16)
             | (((a >> 16) & 0xFFull) << 32) | ((( a >> 24) & 0xFFull) << 48);
    };
    auto unpackHi = [](unsigned long long a) {
        return ((a >> 32) & 0xFFull)        | ((( a >> 40) & 0xFFull) << 16)
             | (((a >> 48) & 0xFFull) << 32) | ((( a >> 56) & 0xFFull) << 48);
    };
    unsigned long long sAllLo = unpackLo(aAll), sAllHi = unpackHi(aAll);
    unsigned long long sBefLo = unpackLo(aBef), sBefHi = unpackHi(aBef);
    #pragma unroll
    for (int off = 32; off > 0; off >>= 1) {
        sAllLo += __shfl_down(sAllLo, off, 64);
        sAllHi += __shfl_down(sAllHi, off, 64);
        sBefLo += __shfl_down(sBefLo, off, 64);
        sBefHi += __shfl_down(sBefHi, off, 64);
    }
    if (lane == 0) {
        #pragma unroll
        for (int e = 0; e < 4; e++) {
            atomicAdd(&cntAll[e],     (int)((sAllLo >> (e * 16)) & 0xFFFF));
            atomicAdd(&cntAll[e + 4], (int)((sAllHi >> (e * 16)) & 0xFFFF));
            atomicAdd(&cntBef[e],     (int)((sBefLo >> (e * 16)) & 0xFFFF));
            atomicAdd(&cntBef[e + 4], (int)((sBefHi >> (e * 16)) & 0xFFFF));
        }
    }
    __syncthreads();
    if (tid < NE) {
        int offs = 0;
        for (int ee = 0; ee < tid; ee++) offs += cntAll[ee];
        cur[tid] = offs + cntBef[tid];
        if (b == 0) { counts[tid] = cntAll[tid]; offsets[tid] = offs; }
    }
    __syncthreads();
    const int t = b * 256 + tid;
    #pragma unroll
    for (int k = 0; k < 2; k++) {
        int e = top_idx[t * 2 + k];
        int slot = atomicAdd(&cur[e], 1);
        rows[slot] = t;
        gates[slot] = top_p[t * 2 + k];
        slot_of[t * 2 + k] = slot;
    }
}

// map compact tile id gy -> (expert e, tile mt); returns false past the end
__device__ __forceinline__ bool tile_lookup(const int* counts, const int* offsets, int gy,
                                            int& e, int& mt, int& cnt, int& off) {
    int bacc = 0;
    #pragma unroll
    for (int ee = 0; ee < NE; ee++) {
        int c = counts[ee];
        int ntl = (c + BM - 1) >> 7;
        if (gy < bacc + ntl) { e = ee; mt = gy - bacc; cnt = c; off = offsets[ee]; return true; }
        bacc += ntl;
    }
    return false;
}

// ---------------- GEMM1: H = silu(X*W1) .* (X*W3), bf16 out ----------------
// 128(slots) x 64(cols of BOTH W1,W3), BK=64, single-buffered global_load_lds.
// R11 win (kept): launch_bounds(256,4) + two-pass fragment loading (b3f
// reuses b1f's registers) — VGPR 80->60 arch, 4 blocks/CU, 49.2->45.0 us.
__global__ __launch_bounds__(256, 4) void gemm1_kernel(
    const unsigned short* __restrict__ xb,     // [TOKENS][DM]
    const unsigned short* __restrict__ w1t,    // [E][HID][DM]
    const unsigned short* __restrict__ w3t,    // [E][HID][DM]
    unsigned short* __restrict__ Hb,           // [NSLOT][HID]
    const int* __restrict__ rows, const int* __restrict__ counts,
    const int* __restrict__ offsets) {
    const int lid = blockIdx.x;                // 0 .. 16*MAXTILE-1
    const int xcd = lid & 7;
    const int j = lid >> 3;                    // 0..271
    const int gy = xcd * (MAXTILE / 8) + (j >> 4);
    const int nt = j & 15;
    int e, mt, cnt, off;
    if (!tile_lookup(counts, offsets, gy, e, mt, cnt, off)) return;

    __shared__ unsigned short As[BM * BK];     // 16 KB
    __shared__ unsigned short B1s[BN * BK];    // 8 KB
    __shared__ unsigned short B3s[BN * BK];    // 8 KB

    const int tid = threadIdx.x;
    const int lane = tid & 63, wave = tid >> 6;
    const int lrow8 = lane >> 3;               // 0..7
    const int lchunk = (lane & 7) ^ lrow8;     // swizzled global chunk this lane fetches

    const unsigned short* a_g[4];
    #pragma unroll
    for (int i = 0; i < 4; i++) {
        int r = (wave * 4 + i) * 8 + lrow8;    // 0..127
        int gr = mt * BM + r;
        int tok = rows[off + (gr < cnt ? gr : 0)];
        a_g[i] = xb + (size_t)tok * DM + lchunk * 8;
    }
    const unsigned short* b1_g[2]; const unsigned short* b3_g[2];
    #pragma unroll
    for (int i = 0; i < 2; i++) {
        int r = (wave * 2 + i) * 8 + lrow8;    // 0..63
        b1_g[i] = w1t + ((size_t)e * HID + nt * BN + r) * DM + lchunk * 8;
        b3_g[i] = w3t + ((size_t)e * HID + nt * BN + r) * DM + lchunk * 8;
    }

    const int l15 = lane & 15, quad = lane >> 4;
    const int sw = l15 & 7;

    floatx4 acc1[2][4], acc3[2][4];
    #pragma unroll
    for (int i = 0; i < 2; i++)
        #pragma unroll
        for (int j2 = 0; j2 < 4; j2++) {
            acc1[i][j2] = (floatx4){0.f, 0.f, 0.f, 0.f};
            acc3[i][j2] = (floatx4){0.f, 0.f, 0.f, 0.f};
        }

    auto stage = [&](int k0) {
        #pragma unroll
        for (int i = 0; i < 4; i++) load16_lds(a_g[i] + k0, &As[(wave * 4 + i) * 512]);
        #pragma unroll
        for (int i = 0; i < 2; i++) {
            load16_lds(b1_g[i] + k0, &B1s[(wave * 2 + i) * 512]);
            load16_lds(b3_g[i] + k0, &B3s[(wave * 2 + i) * 512]);
        }
    };
    auto compute = [&]() {
        #pragma unroll
        for (int kk = 0; kk < 2; kk++) {
            const int qc = kk * 4 + quad;
            const int ch = (qc ^ sw) << 3;
            bf16x8 af[2], bfrag[4];
            #pragma unroll
            for (int mi = 0; mi < 2; mi++)
                af[mi] = *(const bf16x8*)(&As[(wave * 32 + mi * 16 + l15) * 64 + ch]);
            // pass 1: W1 fragments -> acc1
            #pragma unroll
            for (int ni = 0; ni < 4; ni++)
                bfrag[ni] = *(const bf16x8*)(&B1s[(ni * 16 + l15) * 64 + ch]);
            #pragma unroll
            for (int mi = 0; mi < 2; mi++)
                #pragma unroll
                for (int ni = 0; ni < 4; ni++)
                    acc1[mi][ni] = __builtin_amdgcn_mfma_f32_16x16x32_bf16(af[mi], bfrag[ni], acc1[mi][ni], 0, 0, 0);
            // pass 2: W3 fragments reuse the same registers -> acc3
            #pragma unroll
            for (int ni = 0; ni < 4; ni++)
                bfrag[ni] = *(const bf16x8*)(&B3s[(ni * 16 + l15) * 64 + ch]);
            #pragma unroll
            for (int mi = 0; mi < 2; mi++)
                #pragma unroll
                for (int ni = 0; ni < 4; ni++)
                    acc3[mi][ni] = __builtin_amdgcn_mfma_f32_16x16x32_bf16(af[mi], bfrag[ni], acc3[mi][ni], 0, 0, 0);
        }
    };

    const int NI = DM / BK;   // 8
    #pragma unroll
    for (int i = 0; i < NI; i++) {
        if (i) __syncthreads();               // prior reads of LDS done before overwrite
        stage(i * BK);
        __syncthreads();                      // vmcnt drained: tile staged
        compute();
    }
    // epilogue: silu(z1)*z3 -> bf16; C/D: col=l15, row=quad*4+r
    #pragma unroll
    for (int mi = 0; mi < 2; mi++) {
        #pragma unroll
        for (int r = 0; r < 4; r++) {
            int mloc = wave * 32 + mi * 16 + quad * 4 + r;
            int gi = mt * BM + mloc;
            if (gi < cnt) {
                size_t rowbase = (size_t)(off + gi) * HID + nt * BN;
                #pragma unroll
                for (int ni = 0; ni < 4; ni++) {
                    float z1 = acc1[mi][ni][r];
                    float z3 = acc3[mi][ni][r];
                    float h = (z1 / (1.f + __expf(-z1))) * z3;
                    Hb[rowbase + ni * 16 + l15] = f2bf(h);
                }
            }
        }
    }
}

// ------- GEMM2 + fused combine: P then y via completion counters -------------
// 128x128 tile (R10-proven body). Epilogue: store gated bf16 P rows,
// __threadfence (release), one lane per row bumps ctr[tok]; the 8th arriver
// (2 slots x 4 col-groups = 8 fragments, all from DIFFERENT blocks) appends
// the token to an LDS list; after __syncthreads + __threadfence (acquire),
// the block's waves combine listed tokens into y. No waiting loops anywhere
// -> no hang possible (R8 lesson); G16-sanctioned device-scope atomics+fences.
__global__ __launch_bounds__(256) void gemm2_kernel(
    const unsigned short* __restrict__ Hb,    // [NSLOT][HID]
    const unsigned short* __restrict__ w2t,   // [E][DM][HID]
    unsigned short* __restrict__ P,           // [NSLOT][DM] bf16, gated
    const float* __restrict__ gates,
    const int* __restrict__ rows, const int* __restrict__ slot_of,
    int* __restrict__ ctr, float* __restrict__ y,
    const int* __restrict__ counts, const int* __restrict__ offsets) {
    const int lid = blockIdx.x;                // 0 .. 4*MAXTILE-1
    const int xcd = lid & 7;
    const int j = lid >> 3;                    // 0..67
    const int gy = xcd * (MAXTILE / 8) + (j >> 2);
    const int nt = j & 3;                      // 4 col-groups of 128
    int e, mt, cnt, off;
    if (!tile_lookup(counts, offsets, gy, e, mt, cnt, off)) return;

    __shared__ unsigned short As[BM * BK];     // 16 KB
    __shared__ unsigned short Bs[BN2 * BK];    // 16 KB
    __shared__ int nlist;
    __shared__ int list[BM];

    const int tid = threadIdx.x;
    const int lane = tid & 63, wave = tid >> 6;
    const int lrow8 = lane >> 3;
    const int lchunk = (lane & 7) ^ lrow8;

    const unsigned short* a_g[4];
    #pragma unroll
    for (int i = 0; i < 4; i++) {
        int r = (wave * 4 + i) * 8 + lrow8;    // 0..127
        int sl = off + mt * BM + r;
        if (sl >= NSLOT) sl = NSLOT - 1;      // clamp (ragged tail), value unused
        a_g[i] = Hb + (size_t)sl * HID + lchunk * 8;
    }
    const unsigned short* b_g[4];
    #pragma unroll
    for (int i = 0; i < 4; i++) {
        int r = (wave * 4 + i) * 8 + lrow8;    // 0..127
        b_g[i] = w2t + ((size_t)e * DM + nt * BN2 + r) * HID + lchunk * 8;
    }

    const int l15 = lane & 15, quad = lane >> 4;
    const int sw = l15 & 7;

    floatx4 acc[2][8];
    #pragma unroll
    for (int i = 0; i < 2; i++)
        #pragma unroll
        for (int j2 = 0; j2 < 8; j2++) acc[i][j2] = (floatx4){0.f, 0.f, 0.f, 0.f};

    auto stage = [&](int k0) {
        #pragma unroll
        for (int i = 0; i < 4; i++) load16_lds(a_g[i] + k0, &As[(wave * 4 + i) * 512]);
        #pragma unroll
        for (int i = 0; i < 4; i++) load16_lds(b_g[i] + k0, &Bs[(wave * 4 + i) * 512]);
    };
    auto compute = [&]() {
        #pragma unroll
        for (int kk = 0; kk < 2; kk++) {
            const int qc = kk * 4 + quad;
            const int ch = (qc ^ sw) << 3;
            bf16x8 af[2], bf[8];
            #pragma unroll
            for (int mi = 0; mi < 2; mi++)
                af[mi] = *(const bf16x8*)(&As[(wave * 32 + mi * 16 + l15) * 64 + ch]);
            #pragma unroll
            for (int ni = 0; ni < 8; ni++)
                bf[ni] = *(const bf16x8*)(&Bs[(ni * 16 + l15) * 64 + ch]);
            #pragma unroll
            for (int mi = 0; mi < 2; mi++)
                #pragma unroll
                for (int ni = 0; ni < 8; ni++)
                    acc[mi][ni] = __builtin_amdgcn_mfma_f32_16x16x32_bf16(af[mi], bf[ni], acc[mi][ni], 0, 0, 0);
        }
    };

    const int NI = HID / BK;   // 16
    #pragma unroll
    for (int i = 0; i < NI; i++) {
        if (i) __syncthreads();
        stage(i * BK);
        __syncthreads();
        compute();
    }
    if (tid == 0) nlist = 0;
    __syncthreads();
    // ---- P stores (unchanged) ----
    #pragma unroll
    for (int mi = 0; mi < 2; mi++) {
        #pragma unroll
        for (int r = 0; r < 4; r++) {
            int mloc = wave * 32 + mi * 16 + quad * 4 + r;
            int gi = mt * BM + mloc;
            if (gi < cnt) {
                int slot = off + gi;
                float g = gates[slot];
                #pragma unroll
                for (int ni = 0; ni < 8; ni++) {
                    int col = nt * BN2 + ni * 16 + l15;
                    P[(size_t)slot * DM + col] = f2bf(g * acc[mi][ni][r]);
                }
            }
        }
    }
    // ---- release: this wave's stores visible device-wide before bumps ----
    __threadfence();
    if (l15 == 0) {
        #pragma unroll
        for (int mi = 0; mi < 2; mi++) {
            #pragma unroll
            for (int r = 0; r < 4; r++) {
                int mloc = wave * 32 + mi * 16 + quad * 4 + r;
                int gi = mt * BM + mloc;
                if (gi < cnt) {
                    int tok = rows[off + gi] & (TOKENS - 1);
                    int old = atomicAdd(&ctr[tok], 1);
                    if (old == 7) {            // 8th fragment: token complete
                        int ix = atomicAdd(&nlist, 1);
                        list[ix] = tok;
                    }
                }
            }
        }
    }
    __syncthreads();
    __threadfence();   // acquire: other blocks' P stores visible for reads
    const int nl = nlist;
    for (int i = wave; i < nl; i += 4) {
        int t = list[i];
        int s0 = slot_of[t * 2] & (NSLOT - 1);
        int s1 = slot_of[t * 2 + 1] & (NSLOT - 1);
        uint4 a = *(const uint4*)(P + (size_t)s0 * DM + lane * 8);
        uint4 b = *(const uint4*)(P + (size_t)s1 * DM + lane * 8);
        float o[8];
        const unsigned* aw = (const unsigned*)&a;
        const unsigned* bw = (const unsigned*)&b;
        #pragma unroll
        for (int jj = 0; jj < 4; jj++) {
            union { unsigned u; float f; } al, ah, bl, bh;
            al.u = aw[jj] << 16; ah.u = aw[jj] & 0xffff0000u;
            bl.u = bw[jj] << 16; bh.u = bw[jj] & 0xffff0000u;
            o[jj * 2]     = al.f + bl.f;
            o[jj * 2 + 1] = ah.f + bh.f;
        }
        float4* yo = (float4*)(y + (size_t)t * DM + lane * 8);
        yo[0] = make_float4(o[0], o[1], o[2], o[3]);
        yo[1] = make_float4(o[4], o[5], o[6], o[7]);
    }
}

extern "C" void kernel_launch(void* const* d_in, const int* in_sizes, int n_in,
                              void* d_out, int out_size, void* d_ws, size_t ws_size,
                              hipStream_t stream) {
    (void)in_sizes; (void)n_in; (void)out_size; (void)ws_size;
    const float* x  = (const float*)d_in[0];
    const float* Wg = (const float*)d_in[1];
    const float* bg = (const float*)d_in[2];
    const float* W1 = (const float*)d_in[3];
    const float* W3 = (const float*)d_in[4];
    const float* W2 = (const float*)d_in[5];
    float* y = (float*)d_out;

    // carve order = R5/R10 proven layout (xb at offset 0) — R9's reorder cost
    // gemm1 FETCH +4.7MB / +13us (L2 aliasing), confirmed by R10's revert.
    char* p = (char*)d_ws;
    auto carve = [&](size_t bytes) -> char* {
        char* r = p;
        p += (bytes + 255) & ~(size_t)255;
        return r;
    };
    unsigned short* xb   = (unsigned short*)carve((size_t)TOKENS * DM * 2);
    unsigned short* w1t  = (unsigned short*)carve((size_t)NE * DM * HID * 2);   // 8 MB
    unsigned short* w3t  = (unsigned short*)carve((size_t)NE * DM * HID * 2);   // 8 MB (contiguous)
    unsigned short* w2t  = (unsigned short*)carve((size_t)NE * HID * DM * 2);
    unsigned short* Hb   = (unsigned short*)carve((size_t)NSLOT * HID * 2);
    int*   rows    = (int*)carve(NSLOT * 4);
    float* gates   = (float*)carve(NSLOT * 4);
    int*   slot_of = (int*)carve(NSLOT * 4);
    int*   tidx    = (int*)carve((size_t)TOKENS * 2 * 4);
    float* tp      = (float*)carve((size_t)TOKENS * 2 * 4);
    int*   counts  = (int*)carve(256);
    int*   offsets = (int*)carve(256);
    int*   ctr     = (int*)carve((size_t)TOKENS * 4);
    // P (bf16, 16 MB) aliases w1t+w3t (16 MB) — dead after gemm1 completes.
    unsigned short* P = w1t;

    prep_kernel<<<dim3(3072 + TOKENS / 4), dim3(256), 0, stream>>>(
        x, Wg, bg, W1, W3, W2, w1t, w3t, w2t, tidx, tp, xb);
    sortbuild_kernel<<<dim3(NB), dim3(256), 0, stream>>>(
        tidx, tp, counts, offsets, rows, gates, slot_of, ctr);
    gemm1_kernel<<<dim3((HID / BN) * MAXTILE), dim3(256), 0, stream>>>(xb, w1t, w3t, Hb, rows, counts, offsets);
    gemm2_kernel<<<dim3((DM / BN2) * MAXTILE), dim3(256), 0, stream>>>(
        Hb, w2t, P, gates, rows, slot_of, ctr, y, counts, offsets);
}

// Round 14
// 193.065 us; speedup vs baseline: 1.7983x; 1.7983x over previous
//
#include <hip/hip_runtime.h>
#include <hip/hip_bf16.h>

#define TOKENS 8192
#define DM 512
#define NE 8
#define HID 1024
#define NSLOT (TOKENS * 2)
#define NB 32          // token chunks for sortbuild (256 tokens each)

#define BM 128
#define BN 64
#define BK 64
#define BN2 128        // gemm2 N-tile
#define MAXTILE 136    // 8 * 17, > sum ceil(counts[e]/BM) worst case (135)

typedef __bf16 bf16x8 __attribute__((ext_vector_type(8)));
typedef float floatx4 __attribute__((ext_vector_type(4)));
typedef unsigned short u16x8 __attribute__((ext_vector_type(8)));

__device__ __forceinline__ unsigned short f2bf(float f) {
    union { float f; unsigned u; } c; c.f = f;
    unsigned u = c.u;
    u += 0x7fffu + ((u >> 16) & 1u);   // RNE
    return (unsigned short)(u >> 16);
}

// async global->LDS, 16B per lane, LDS dest = wave-uniform base + lane*16
__device__ __forceinline__ void load16_lds(const void* g, void* l) {
    __builtin_amdgcn_global_load_lds(
        (const __attribute__((address_space(1))) unsigned int*)g,
        (__attribute__((address_space(3))) unsigned int*)l, 16, 0, 0);
}

// ------- prep: fused weight-convert/transpose + router ----------------------
// blocks [0,3072): all 3 weights [E][K][N] fp32 -> [E][N][K] bf16 (64x64 tiles)
// blocks [3072,5120): router (fp32 logits, top-2, softmax over 2) + x->bf16.
// [R6-R8,R13: ALL device-scope ordering inside hot kernels is off the table
// on this 8-XCD part — grid.sync ~100us each (R7), spin barrier hung (R8),
// threadfence handoff stretched gemm2 8x (R13). Kernel boundaries only.]
__global__ void prep_kernel(const float* __restrict__ x, const float* __restrict__ Wg,
                            const float* __restrict__ bg,
                            const float* __restrict__ W1, const float* __restrict__ W3,
                            const float* __restrict__ W2,
                            unsigned short* __restrict__ w1t, unsigned short* __restrict__ w3t,
                            unsigned short* __restrict__ w2t,
                            int* __restrict__ top_idx, float* __restrict__ top_p,
                            unsigned short* __restrict__ xb) {
    if (blockIdx.x < 3072) {
        // ---------- cvt/transpose role ----------
        __shared__ float tile[64][65];
        const int cb = blockIdx.x;
        const int wsel = cb >> 10;               // 0,1,2
        const float* src; unsigned short* dst; int K, N;
        if (wsel == 0)      { src = W1; dst = w1t; K = DM;  N = HID; }
        else if (wsel == 1) { src = W3; dst = w3t; K = DM;  N = HID; }
        else                { src = W2; dst = w2t; K = HID; N = DM;  }
        const int tkn = (K >> 6) * (N >> 6);     // 128 for all three
        int b = cb & 1023;                       // 0 .. NE*tkn-1 (== 1024)
        int e = b / tkn;
        int rem = b % tkn;
        const int tn6 = N >> 6;
        int kt = rem / tn6, nt = rem % tn6;
        int tx = threadIdx.x & 15, ty = threadIdx.x >> 4;   // 16 x 16
        const float* s = src + ((size_t)(e * K + kt * 64 + ty)) * N + nt * 64 + tx * 4;
        #pragma unroll
        for (int i = 0; i < 4; i++) {
            float4 v = *(const float4*)(s + (size_t)(i * 16) * N);
            float* tr = &tile[ty + i * 16][tx * 4];
            tr[0] = v.x; tr[1] = v.y; tr[2] = v.z; tr[3] = v.w;
        }
        __syncthreads();
        int n = threadIdx.x >> 3;                // 0..31
        int c8 = (threadIdx.x & 7) * 8;          // k offset within tile
        unsigned short* d = dst + ((size_t)(e * N + nt * 64)) * K + kt * 64;
        #pragma unroll
        for (int i = 0; i < 2; i++) {
            int nn = n + i * 32;
            u16x8 r;
            #pragma unroll
            for (int kk = 0; kk < 8; kk++) r[kk] = f2bf(tile[c8 + kk][nn]);
            *(u16x8*)(d + (size_t)nn * K + c8) = r;
        }
    } else {
        // ---------- router role ----------
        int lane = threadIdx.x & 63, wave = threadIdx.x >> 6;
        int t = (blockIdx.x - 3072) * 4 + wave;
        float acc[NE];
        #pragma unroll
        for (int e = 0; e < NE; e++) acc[e] = 0.f;
        const float* xr = x + (size_t)t * DM;
        unsigned short* xbr = xb + (size_t)t * DM;
        #pragma unroll
        for (int j = 0; j < 8; j++) {
            int d = lane + j * 64;
            float xv = xr[d];
            xbr[d] = f2bf(xv);
            const float4* wr = (const float4*)(Wg + (size_t)d * NE);
            float4 w0 = wr[0], w1 = wr[1];
            acc[0] += xv * w0.x; acc[1] += xv * w0.y; acc[2] += xv * w0.z; acc[3] += xv * w0.w;
            acc[4] += xv * w1.x; acc[5] += xv * w1.y; acc[6] += xv * w1.z; acc[7] += xv * w1.w;
        }
        #pragma unroll
        for (int e = 0; e < NE; e++) {
            float v = acc[e];
            #pragma unroll
            for (int off = 32; off > 0; off >>= 1) v += __shfl_down(v, off, 64);
            acc[e] = v;
        }
        if (lane == 0) {
            float best = -1e30f, second = -1e30f;
            int bi = 0, si = 0;
            #pragma unroll
            for (int e = 0; e < NE; e++) {
                float v = acc[e] + bg[e];
                if (v > best) { second = best; si = bi; best = v; bi = e; }
                else if (v > second) { second = v; si = e; }
            }
            float ex = __expf(second - best);
            float inv = 1.f / (1.f + ex);
            top_idx[t * 2] = bi;  top_idx[t * 2 + 1] = si;
            top_p[t * 2] = inv;   top_p[t * 2 + 1] = ex * inv;
        }
    }
}

// ------- sortbuild: hist + prefix + build in ONE node, NO cross-block dep ----
// Each of the 32 blocks redundantly scans ALL 16K top_idx entries (128 KB,
// L2-resident) with packed 8x8-bit per-thread counters (aAll; aBef for chunks
// < b — wave-uniform predicate). Unpack to 16-bit fields, 6-step __shfl_down,
// lane-0 LDS merge. Zero inter-block communication. [proven R10]
__global__ void sortbuild_kernel(const int* __restrict__ top_idx, const float* __restrict__ top_p,
                                 int* __restrict__ counts, int* __restrict__ offsets,
                                 int* __restrict__ rows, float* __restrict__ gates,
                                 int* __restrict__ slot_of) {
    __shared__ int cntAll[NE], cntBef[NE], cur[NE];
    const int b = blockIdx.x, tid = threadIdx.x;
    const int lane = tid & 63;
    if (tid < NE) { cntAll[tid] = 0; cntBef[tid] = 0; }
    __syncthreads();

    unsigned long long aAll = 0ull, aBef = 0ull;
    for (int k = 0; k < TOKENS / 256; k++) {       // 32 iterations
        int t = k * 256 + tid;
        int2 ei = *(const int2*)(top_idx + (size_t)t * 2);
        unsigned long long inc = (1ull << (ei.x * 8)) + (1ull << (ei.y * 8));
        aAll += inc;
        if (k < b) aBef += inc;                    // wave-uniform predicate
    }
    auto unpackLo = [](unsigned long long a) {
        return ( a        & 0xFFull)        | ((( a >> 8 ) & 0xFFull) << 16)
             | (((a >> 16) & 0xFFull) << 32) | ((( a >> 24) & 0xFFull) << 48);
    };
    auto unpackHi = [](unsigned long long a) {
        return ((a >> 32) & 0xFFull)        | ((( a >> 40) & 0xFFull) << 16)
             | (((a >> 48) & 0xFFull) << 32) | ((( a >> 56) & 0xFFull) << 48);
    };
    unsigned long long sAllLo = unpackLo(aAll), sAllHi = unpackHi(aAll);
    unsigned long long sBefLo = unpackLo(aBef), sBefHi = unpackHi(aBef);
    #pragma unroll
    for (int off = 32; off > 0; off >>= 1) {
        sAllLo += __shfl_down(sAllLo, off, 64);
        sAllHi += __shfl_down(sAllHi, off, 64);
        sBefLo += __shfl_down(sBefLo, off, 64);
        sBefHi += __shfl_down(sBefHi, off, 64);
    }
    if (lane == 0) {
        #pragma unroll
        for (int e = 0; e < 4; e++) {
            atomicAdd(&cntAll[e],     (int)((sAllLo >> (e * 16)) & 0xFFFF));
            atomicAdd(&cntAll[e + 4], (int)((sAllHi >> (e * 16)) & 0xFFFF));
            atomicAdd(&cntBef[e],     (int)((sBefLo >> (e * 16)) & 0xFFFF));
            atomicAdd(&cntBef[e + 4], (int)((sBefHi >> (e * 16)) & 0xFFFF));
        }
    }
    __syncthreads();
    if (tid < NE) {
        int offs = 0;
        for (int ee = 0; ee < tid; ee++) offs += cntAll[ee];
        cur[tid] = offs + cntBef[tid];
        if (b == 0) { counts[tid] = cntAll[tid]; offsets[tid] = offs; }
    }
    __syncthreads();
    const int t = b * 256 + tid;
    #pragma unroll
    for (int k = 0; k < 2; k++) {
        int e = top_idx[t * 2 + k];
        int slot = atomicAdd(&cur[e], 1);
        rows[slot] = t;
        gates[slot] = top_p[t * 2 + k];
        slot_of[t * 2 + k] = slot;
    }
}

// map compact tile id gy -> (expert e, tile mt); returns false past the end
__device__ __forceinline__ bool tile_lookup(const int* counts, const int* offsets, int gy,
                                            int& e, int& mt, int& cnt, int& off) {
    int bacc = 0;
    #pragma unroll
    for (int ee = 0; ee < NE; ee++) {
        int c = counts[ee];
        int ntl = (c + BM - 1) >> 7;
        if (gy < bacc + ntl) { e = ee; mt = gy - bacc; cnt = c; off = offsets[ee]; return true; }
        bacc += ntl;
    }
    return false;
}

// ---------------- GEMM1: H = silu(X*W1) .* (X*W3), bf16 out ----------------
// 128(slots) x 64(cols of BOTH W1,W3), BK=64, single-buffered global_load_lds.
// R11 win (kept): launch_bounds(256,4) + two-pass fragment loading (b3f
// reuses b1f's registers) — VGPR 80->60 arch (124 unified), 4 blocks/CU,
// 49.2->45.0 us (per-kernel counters, R11/R12).
__global__ __launch_bounds__(256, 4) void gemm1_kernel(
    const unsigned short* __restrict__ xb,     // [TOKENS][DM]
    const unsigned short* __restrict__ w1t,    // [E][HID][DM]
    const unsigned short* __restrict__ w3t,    // [E][HID][DM]
    unsigned short* __restrict__ Hb,           // [NSLOT][HID]
    const int* __restrict__ rows, const int* __restrict__ counts,
    const int* __restrict__ offsets) {
    const int lid = blockIdx.x;                // 0 .. 16*MAXTILE-1
    const int xcd = lid & 7;
    const int j = lid >> 3;                    // 0..271
    const int gy = xcd * (MAXTILE / 8) + (j >> 4);
    const int nt = j & 15;
    int e, mt, cnt, off;
    if (!tile_lookup(counts, offsets, gy, e, mt, cnt, off)) return;

    __shared__ unsigned short As[BM * BK];     // 16 KB
    __shared__ unsigned short B1s[BN * BK];    // 8 KB
    __shared__ unsigned short B3s[BN * BK];    // 8 KB

    const int tid = threadIdx.x;
    const int lane = tid & 63, wave = tid >> 6;
    const int lrow8 = lane >> 3;               // 0..7
    const int lchunk = (lane & 7) ^ lrow8;     // swizzled global chunk this lane fetches

    const unsigned short* a_g[4];
    #pragma unroll
    for (int i = 0; i < 4; i++) {
        int r = (wave * 4 + i) * 8 + lrow8;    // 0..127
        int gr = mt * BM + r;
        int tok = rows[off + (gr < cnt ? gr : 0)];
        a_g[i] = xb + (size_t)tok * DM + lchunk * 8;
    }
    const unsigned short* b1_g[2]; const unsigned short* b3_g[2];
    #pragma unroll
    for (int i = 0; i < 2; i++) {
        int r = (wave * 2 + i) * 8 + lrow8;    // 0..63
        b1_g[i] = w1t + ((size_t)e * HID + nt * BN + r) * DM + lchunk * 8;
        b3_g[i] = w3t + ((size_t)e * HID + nt * BN + r) * DM + lchunk * 8;
    }

    const int l15 = lane & 15, quad = lane >> 4;
    const int sw = l15 & 7;

    floatx4 acc1[2][4], acc3[2][4];
    #pragma unroll
    for (int i = 0; i < 2; i++)
        #pragma unroll
        for (int j2 = 0; j2 < 4; j2++) {
            acc1[i][j2] = (floatx4){0.f, 0.f, 0.f, 0.f};
            acc3[i][j2] = (floatx4){0.f, 0.f, 0.f, 0.f};
        }

    auto stage = [&](int k0) {
        #pragma unroll
        for (int i = 0; i < 4; i++) load16_lds(a_g[i] + k0, &As[(wave * 4 + i) * 512]);
        #pragma unroll
        for (int i = 0; i < 2; i++) {
            load16_lds(b1_g[i] + k0, &B1s[(wave * 2 + i) * 512]);
            load16_lds(b3_g[i] + k0, &B3s[(wave * 2 + i) * 512]);
        }
    };
    auto compute = [&]() {
        #pragma unroll
        for (int kk = 0; kk < 2; kk++) {
            const int qc = kk * 4 + quad;
            const int ch = (qc ^ sw) << 3;
            bf16x8 af[2], bfrag[4];
            #pragma unroll
            for (int mi = 0; mi < 2; mi++)
                af[mi] = *(const bf16x8*)(&As[(wave * 32 + mi * 16 + l15) * 64 + ch]);
            // pass 1: W1 fragments -> acc1
            #pragma unroll
            for (int ni = 0; ni < 4; ni++)
                bfrag[ni] = *(const bf16x8*)(&B1s[(ni * 16 + l15) * 64 + ch]);
            #pragma unroll
            for (int mi = 0; mi < 2; mi++)
                #pragma unroll
                for (int ni = 0; ni < 4; ni++)
                    acc1[mi][ni] = __builtin_amdgcn_mfma_f32_16x16x32_bf16(af[mi], bfrag[ni], acc1[mi][ni], 0, 0, 0);
            // pass 2: W3 fragments reuse the same registers -> acc3
            #pragma unroll
            for (int ni = 0; ni < 4; ni++)
                bfrag[ni] = *(const bf16x8*)(&B3s[(ni * 16 + l15) * 64 + ch]);
            #pragma unroll
            for (int mi = 0; mi < 2; mi++)
                #pragma unroll
                for (int ni = 0; ni < 4; ni++)
                    acc3[mi][ni] = __builtin_amdgcn_mfma_f32_16x16x32_bf16(af[mi], bfrag[ni], acc3[mi][ni], 0, 0, 0);
        }
    };

    const int NI = DM / BK;   // 8
    #pragma unroll
    for (int i = 0; i < NI; i++) {
        if (i) __syncthreads();               // prior reads of LDS done before overwrite
        stage(i * BK);
        __syncthreads();                      // vmcnt drained: tile staged
        compute();
    }
    // epilogue: silu(z1)*z3 -> bf16; C/D: col=l15, row=quad*4+r
    #pragma unroll
    for (int mi = 0; mi < 2; mi++) {
        #pragma unroll
        for (int r = 0; r < 4; r++) {
            int mloc = wave * 32 + mi * 16 + quad * 4 + r;
            int gi = mt * BM + mloc;
            if (gi < cnt) {
                size_t rowbase = (size_t)(off + gi) * HID + nt * BN;
                #pragma unroll
                for (int ni = 0; ni < 4; ni++) {
                    float z1 = acc1[mi][ni][r];
                    float z3 = acc3[mi][ni][r];
                    float h = (z1 / (1.f + __expf(-z1))) * z3;
                    Hb[rowbase + ni * 16 + l15] = f2bf(h);
                }
            }
        }
    }
}

// ------- GEMM2: P[slot] = bf16(gates[slot] * (H[slot] @ W2)) — no atomics --------
// BN2=128: 128x128 tile, 32 KB single-buffered (R10-proven, ~25us).
// [R13 post-mortem: threadfence-based fused combine stretched this kernel
// 25->194us (device-scope fences + cross-XCD P reads). Reverted.]
__global__ __launch_bounds__(256) void gemm2_kernel(
    const unsigned short* __restrict__ Hb,    // [NSLOT][HID]
    const unsigned short* __restrict__ w2t,   // [E][DM][HID]
    unsigned short* __restrict__ P,           // [NSLOT][DM] bf16, gated
    const float* __restrict__ gates,
    const int* __restrict__ counts, const int* __restrict__ offsets) {
    const int lid = blockIdx.x;                // 0 .. 4*MAXTILE-1
    const int xcd = lid & 7;
    const int j = lid >> 3;                    // 0..67
    const int gy = xcd * (MAXTILE / 8) + (j >> 2);
    const int nt = j & 3;                      // 4 col-groups of 128
    int e, mt, cnt, off;
    if (!tile_lookup(counts, offsets, gy, e, mt, cnt, off)) return;

    __shared__ unsigned short As[BM * BK];     // 16 KB
    __shared__ unsigned short Bs[BN2 * BK];    // 16 KB

    const int tid = threadIdx.x;
    const int lane = tid & 63, wave = tid >> 6;
    const int lrow8 = lane >> 3;
    const int lchunk = (lane & 7) ^ lrow8;

    const unsigned short* a_g[4];
    #pragma unroll
    for (int i = 0; i < 4; i++) {
        int r = (wave * 4 + i) * 8 + lrow8;    // 0..127
        int sl = off + mt * BM + r;
        if (sl >= NSLOT) sl = NSLOT - 1;      // clamp (ragged tail), value unused
        a_g[i] = Hb + (size_t)sl * HID + lchunk * 8;
    }
    const unsigned short* b_g[4];
    #pragma unroll
    for (int i = 0; i < 4; i++) {
        int r = (wave * 4 + i) * 8 + lrow8;    // 0..127
        b_g[i] = w2t + ((size_t)e * DM + nt * BN2 + r) * HID + lchunk * 8;
    }

    const int l15 = lane & 15, quad = lane >> 4;
    const int sw = l15 & 7;

    floatx4 acc[2][8];
    #pragma unroll
    for (int i = 0; i < 2; i++)
        #pragma unroll
        for (int j2 = 0; j2 < 8; j2++) acc[i][j2] = (floatx4){0.f, 0.f, 0.f, 0.f};

    auto stage = [&](int k0) {
        #pragma unroll
        for (int i = 0; i < 4; i++) load16_lds(a_g[i] + k0, &As[(wave * 4 + i) * 512]);
        #pragma unroll
        for (int i = 0; i < 4; i++) load16_lds(b_g[i] + k0, &Bs[(wave * 4 + i) * 512]);
    };
    auto compute = [&]() {
        #pragma unroll
        for (int kk = 0; kk < 2; kk++) {
            const int qc = kk * 4 + quad;
            const int ch = (qc ^ sw) << 3;
            bf16x8 af[2], bf[8];
            #pragma unroll
            for (int mi = 0; mi < 2; mi++)
                af[mi] = *(const bf16x8*)(&As[(wave * 32 + mi * 16 + l15) * 64 + ch]);
            #pragma unroll
            for (int ni = 0; ni < 8; ni++)
                bf[ni] = *(const bf16x8*)(&Bs[(ni * 16 + l15) * 64 + ch]);
            #pragma unroll
            for (int mi = 0; mi < 2; mi++)
                #pragma unroll
                for (int ni = 0; ni < 8; ni++)
                    acc[mi][ni] = __builtin_amdgcn_mfma_f32_16x16x32_bf16(af[mi], bf[ni], acc[mi][ni], 0, 0, 0);
        }
    };

    const int NI = HID / BK;   // 16
    #pragma unroll
    for (int i = 0; i < NI; i++) {
        if (i) __syncthreads();
        stage(i * BK);
        __syncthreads();
        compute();
    }
    #pragma unroll
    for (int mi = 0; mi < 2; mi++) {
        #pragma unroll
        for (int r = 0; r < 4; r++) {
            int mloc = wave * 32 + mi * 16 + quad * 4 + r;
            int gi = mt * BM + mloc;
            if (gi < cnt) {
                int slot = off + gi;
                float g = gates[slot];
                #pragma unroll
                for (int ni = 0; ni < 8; ni++) {
                    int col = nt * BN2 + ni * 16 + l15;
                    P[(size_t)slot * DM + col] = f2bf(g * acc[mi][ni][r]);
                }
            }
        }
    }
}

// ---------------- combine: y[t] = P[s0] + P[s1] (P bf16, pre-gated) ----------------
__global__ void combine_kernel(const unsigned short* __restrict__ P,
                               const int* __restrict__ slot_of, float* __restrict__ y) {
    int i = blockIdx.x * blockDim.x + threadIdx.x;    // per 8 elems
    int t = i / (DM / 8);
    int c8 = i % (DM / 8);
    int s0 = slot_of[t * 2], s1 = slot_of[t * 2 + 1];
    uint4 a = *(const uint4*)(P + (size_t)s0 * DM + c8 * 8);
    uint4 b = *(const uint4*)(P + (size_t)s1 * DM + c8 * 8);
    float o[8];
    const unsigned* aw = (const unsigned*)&a;
    const unsigned* bw = (const unsigned*)&b;
    #pragma unroll
    for (int j = 0; j < 4; j++) {
        union { unsigned u; float f; } al, ah, bl, bh;
        al.u = aw[j] << 16; ah.u = aw[j] & 0xffff0000u;
        bl.u = bw[j] << 16; bh.u = bw[j] & 0xffff0000u;
        o[j * 2]     = al.f + bl.f;
        o[j * 2 + 1] = ah.f + bh.f;
    }
    float4* yo = (float4*)(y + (size_t)t * DM + c8 * 8);
    yo[0] = make_float4(o[0], o[1], o[2], o[3]);
    yo[1] = make_float4(o[4], o[5], o[6], o[7]);
}

extern "C" void kernel_launch(void* const* d_in, const int* in_sizes, int n_in,
                              void* d_out, int out_size, void* d_ws, size_t ws_size,
                              hipStream_t stream) {
    (void)in_sizes; (void)n_in; (void)out_size; (void)ws_size;
    const float* x  = (const float*)d_in[0];
    const float* Wg = (const float*)d_in[1];
    const float* bg = (const float*)d_in[2];
    const float* W1 = (const float*)d_in[3];
    const float* W3 = (const float*)d_in[4];
    const float* W2 = (const float*)d_in[5];
    float* y = (float*)d_out;

    // carve order = R5/R10 proven layout (xb at offset 0) — R9's reorder cost
    // gemm1 FETCH +4.7MB / +13us (L2 aliasing), confirmed by R10's revert.
    char* p = (char*)d_ws;
    auto carve = [&](size_t bytes) -> char* {
        char* r = p;
        p += (bytes + 255) & ~(size_t)255;
        return r;
    };
    unsigned short* xb   = (unsigned short*)carve((size_t)TOKENS * DM * 2);
    unsigned short* w1t  = (unsigned short*)carve((size_t)NE * DM * HID * 2);   // 8 MB
    unsigned short* w3t  = (unsigned short*)carve((size_t)NE * DM * HID * 2);   // 8 MB (contiguous)
    unsigned short* w2t  = (unsigned short*)carve((size_t)NE * HID * DM * 2);
    unsigned short* Hb   = (unsigned short*)carve((size_t)NSLOT * HID * 2);
    int*   rows    = (int*)carve(NSLOT * 4);
    float* gates   = (float*)carve(NSLOT * 4);
    int*   slot_of = (int*)carve(NSLOT * 4);
    int*   tidx    = (int*)carve((size_t)TOKENS * 2 * 4);
    float* tp      = (float*)carve((size_t)TOKENS * 2 * 4);
    int*   counts  = (int*)carve(256);
    int*   offsets = (int*)carve(256);
    // P (bf16, 16 MB) aliases w1t+w3t (16 MB) — dead after gemm1 completes.
    unsigned short* P = w1t;

    prep_kernel<<<dim3(3072 + TOKENS / 4), dim3(256), 0, stream>>>(
        x, Wg, bg, W1, W3, W2, w1t, w3t, w2t, tidx, tp, xb);
    sortbuild_kernel<<<dim3(NB), dim3(256), 0, stream>>>(
        tidx, tp, counts, offsets, rows, gates, slot_of);
    gemm1_kernel<<<dim3((HID / BN) * MAXTILE), dim3(256), 0, stream>>>(xb, w1t, w3t, Hb, rows, counts, offsets);
    gemm2_kernel<<<dim3((DM / BN2) * MAXTILE), dim3(256), 0, stream>>>(Hb, w2t, P, gates, counts, offsets);
    combine_kernel<<<dim3((TOKENS * DM / 8) / 256), dim3(256), 0, stream>>>(P, slot_of, y);
}